// Round 11
// baseline (303.804 us; speedup 1.0000x reference)
//
#include <hip/hip_runtime.h>

#define TT 1024
#define KK 16
#define HH 20
#define NCELL 1024

typedef _Float16 f16;
typedef f16 f16x2 __attribute__((ext_vector_type(2)));

#define LOG2E 1.4426950408889634f

__device__ __forceinline__ float fdot2(f16x2 a, f16x2 b, float c) {
    // v_dot2_f32_f16: a.x*b.x + a.y*b.y + c, f32 accumulate.
    return __builtin_amdgcn_fdot2(a, b, c, false);
}
__device__ __forceinline__ float fast_rcp(float x) {
    return __builtin_amdgcn_rcpf(x);
}
// sigmoid in exp2 domain (x pre-scaled by log2e): rcp(1 + 2^-x).
__device__ __forceinline__ float sigm2(float x2) {
    return fast_rcp(1.0f + __builtin_amdgcn_exp2f(-x2));
}
// tanh of a TRUE-domain value.
__device__ __forceinline__ float tanh_fast(float x) {
    float e = __builtin_amdgcn_exp2f(x * (2.0f * LOG2E));
    return 1.0f - 2.0f * fast_rcp(e + 1.0f);
}
__device__ __forceinline__ float bcast(float v, int srclane) {
    return __int_as_float(__builtin_amdgcn_readlane(__float_as_int(v), srclane));
}
__device__ __forceinline__ unsigned bcast_u(unsigned v, int srclane) {
    return (unsigned)__builtin_amdgcn_readlane((int)v, srclane);
}

struct F3 { float x, y, z; };

// TWO cells per wave: cell A = lanes 0..19, cell B = lanes 32..51 (lane's
// unit j = lane&31, clamped). Each lane holds ALL FOUR gate rows of its unit
// (f16, pre-scaled by log2e; g-row by 2*log2e) -> no cross-half gate
// exchange, 4 parallel activation chains, c/h update fully lane-local.
// Per-step h broadcast: pack own+neighbor h as f16x2 (cvt+DPP xor1+or), 10
// readlanes per cell, one v_cndmask per pair selects the half's cell.
// Rationale (R10 post-mortem): with 1024 cells on 1024 SIMDs the serial
// dependency chain (~250cy/step) cannot be hidden by other waves; lockstep
// SIMD means a 2nd cell in the idle lanes adds only issue (~90cy), not
// latency -> ~260cy per cell-step vs 434 measured single-cell.
// waves_per_eu(1,1): truthful (512 waves < 1024 SIMDs) -> full register file.
__global__ __launch_bounds__(64)
__attribute__((amdgpu_waves_per_eu(1, 1)))
void lstm_kernel(
    const float* __restrict__ inp,    // [B][T][K][3]
    const float* __restrict__ W_ih,   // [K][80][3]
    const float* __restrict__ W_hh,   // [K][80][20]
    const float* __restrict__ b_ih,   // [K][80]
    const float* __restrict__ b_hh,   // [K][80]
    const float* __restrict__ w,      // [K*B+1]
    const float* __restrict__ conv_w, // [21]
    const float* __restrict__ conv_b, // [1]
    float* __restrict__ y_ws)         // [1024] pre-softmax y for rows 1..1024
{
    const int lane  = threadIdx.x;
    const int bid   = blockIdx.x;          // 0..511
    const int cellA = 2 * bid;
    const int cellB = 2 * bid + 1;
    const bool isA  = (lane < 32);
    const int myCell = isA ? cellA : cellB;
    const int k  = myCell >> 6;
    const int b  = myCell & 63;
    const int jj = lane & 31;
    const int j  = (jj < HH) ? jj : (HH - 1);  // lanes 20..31 / 52..63 shadow

    // Per-lane weights: 4 gate rows (i,f,g,o) of unit j, f16 pre-scaled.
    f16x2 Wh[4][10];     // W_hh pairs
    f16x2 Wx01[4];       // (Wi0, Wi1) pre-scaled
    f16x2 Wx2b[4];       // (Wi2, bias) pre-scaled  (dot with (x2, 1))
    {
        #pragma unroll
        for (int g = 0; g < 4; ++g) {
            const int r = k * 80 + g * HH + j;
            const float scale = LOG2E * ((g == 2) ? 2.0f : 1.0f);
            #pragma unroll
            for (int m = 0; m < 10; ++m) {
                Wh[g][m] = f16x2{(f16)(W_hh[r * HH + 2 * m] * scale),
                                 (f16)(W_hh[r * HH + 2 * m + 1] * scale)};
            }
            Wx01[g] = f16x2{(f16)(W_ih[r * 3 + 0] * scale),
                            (f16)(W_ih[r * 3 + 1] * scale)};
            Wx2b[g] = f16x2{(f16)(W_ih[r * 3 + 2] * scale),
                            (f16)((b_ih[r] + b_hh[r]) * scale)};
        }
    }

    float h_own = 0.0f, c_own = 0.0f;

    // Per-lane input base (cell-dependent): inp[((b*T + t)*K + k)*3].
    const float* xb = inp + (b * TT * KK + k) * 3;
    F3 p0{xb[0 * 48], xb[0 * 48 + 1], xb[0 * 48 + 2]};
    F3 p1{xb[1 * 48], xb[1 * 48 + 1], xb[1 * 48 + 2]};
    F3 p2{xb[2 * 48], xb[2 * 48 + 1], xb[2 * 48 + 2]};
    F3 p3{xb[3 * 48], xb[3 * 48 + 1], xb[3 * 48 + 2]};

    auto step = [&](F3& p, int t) {
        // 1) pack own h with neighbor (f16 pair), per-cell readlane + select.
        unsigned hb = (unsigned)__builtin_bit_cast(unsigned short, (f16)h_own);
        unsigned nb = (unsigned)__builtin_amdgcn_mov_dpp((int)hb, 0xB1, 0xF, 0xF, true);
        const unsigned packed = hb | (nb << 16);  // even lane 2m: (h[2m], h[2m+1])
        f16x2 hp[10];
        #pragma unroll
        for (int m = 0; m < 10; ++m) {
            const unsigned pa = bcast_u(packed, 2 * m);        // cell A pair m
            const unsigned pb = bcast_u(packed, 32 + 2 * m);   // cell B pair m
            hp[m] = __builtin_bit_cast(f16x2, isA ? pa : pb);  // 1 cndmask
        }
        const float x0 = p.x, x1 = p.y, x2 = p.z;
        // 2) refill p for step t+4 (latency spans 4 steps)
        {
            int tn = t + 4; tn = (tn < TT) ? tn : (TT - 1);
            const float* q = xb + tn * (KK * 3);
            p.x = q[0]; p.y = q[1]; p.z = q[2];
        }
        // 3) x packed to f16 (off the h critical path)
        const f16x2 xp01 = f16x2{(f16)x0, (f16)x1};
        const f16x2 xp2b = f16x2{(f16)x2, (f16)1.0f};
        // 4) gate dots: per row, xproj (2 dot2) + 2 chains of 5 dot2
        float a0, a1, a2, a3;
        {
            float q00 = fdot2(Wx01[0], xp01, fdot2(Wx2b[0], xp2b, 0.0f)), q01 = 0.f;
            float q10 = fdot2(Wx01[1], xp01, fdot2(Wx2b[1], xp2b, 0.0f)), q11 = 0.f;
            float q20 = fdot2(Wx01[2], xp01, fdot2(Wx2b[2], xp2b, 0.0f)), q21 = 0.f;
            float q30 = fdot2(Wx01[3], xp01, fdot2(Wx2b[3], xp2b, 0.0f)), q31 = 0.f;
            #pragma unroll
            for (int m = 0; m < 5; ++m) {
                q00 = fdot2(Wh[0][m], hp[m], q00);
                q10 = fdot2(Wh[1][m], hp[m], q10);
                q20 = fdot2(Wh[2][m], hp[m], q20);
                q30 = fdot2(Wh[3][m], hp[m], q30);
                q01 = fdot2(Wh[0][m + 5], hp[m + 5], q01);
                q11 = fdot2(Wh[1][m + 5], hp[m + 5], q11);
                q21 = fdot2(Wh[2][m + 5], hp[m + 5], q21);
                q31 = fdot2(Wh[3][m + 5], hp[m + 5], q31);
            }
            a0 = q00 + q01; a1 = q10 + q11; a2 = q20 + q21; a3 = q30 + q31;
        }
        // 5) activations: 4 parallel chains (exp2 domain)
        const float sI = sigm2(a0);
        const float sF = sigm2(a1);
        const float tG = sigm2(a2) * 2.0f - 1.0f;   // tanh(g)
        const float sO = sigm2(a3);
        // 6) state update (lane-local, no cross-lane)
        c_own = sF * c_own + sI * tG;
        h_own = sO * tanh_fast(c_own);
    };

    for (int tb = 0; tb < TT; tb += 4) {
        step(p0, tb + 0);
        step(p1, tb + 1);
        step(p2, tb + 2);
        step(p3, tb + 3);
    }

    // Epilogue: both cells' y computed uniformly via readlane of f32 h.
    float accA = conv_b[0], accB = conv_b[0];
    #pragma unroll
    for (int hh = 0; hh < HH; ++hh) {
        accA += conv_w[hh] * bcast(h_own, hh);
        accB += conv_w[hh] * bcast(h_own, 32 + hh);
    }
    accA += conv_w[HH] * w[1 + cellA];
    accB += conv_w[HH] * w[1 + cellB];
    if (lane == 0) y_ws[cellA] = tanh_fast(accA);
    if (lane == 1) y_ws[cellB] = tanh_fast(accB);
}

// Softmax over [1, y_0 .. y_1023] -> out[1025]
__global__ __launch_bounds__(256) void softmax_kernel(
    const float* __restrict__ y_ws, float* __restrict__ out)
{
    __shared__ float red[4];
    const int tid = threadIdx.x;
    float vals[5];
    float local = 0.0f;
    #pragma unroll
    for (int it = 0; it < 5; ++it) {
        const int idx = tid + it * 256;
        if (idx < NCELL + 1) {
            const float y = (idx == 0) ? 1.0f : y_ws[idx - 1];
            const float e = __expf(y);
            vals[it] = e;
            local += e;
        } else {
            vals[it] = 0.0f;
        }
    }
    #pragma unroll
    for (int off = 32; off > 0; off >>= 1) local += __shfl_down(local, off, 64);
    if ((tid & 63) == 0) red[tid >> 6] = local;
    __syncthreads();
    const float total = red[0] + red[1] + red[2] + red[3];
    const float inv = 1.0f / total;
    #pragma unroll
    for (int it = 0; it < 5; ++it) {
        const int idx = tid + it * 256;
        if (idx < NCELL + 1) out[idx] = vals[it] * inv;
    }
}

extern "C" void kernel_launch(void* const* d_in, const int* in_sizes, int n_in,
                              void* d_out, int out_size, void* d_ws, size_t ws_size,
                              hipStream_t stream) {
    const float* inp    = (const float*)d_in[0];
    const float* w      = (const float*)d_in[1];
    const float* W_ih   = (const float*)d_in[2];
    const float* W_hh   = (const float*)d_in[3];
    const float* b_ih   = (const float*)d_in[4];
    const float* b_hh   = (const float*)d_in[5];
    const float* conv_w = (const float*)d_in[6];
    const float* conv_b = (const float*)d_in[7];
    float* out  = (float*)d_out;
    float* y_ws = (float*)d_ws;

    lstm_kernel<<<NCELL / 2, 64, 0, stream>>>(inp, W_ih, W_hh, b_ih, b_hh, w,
                                              conv_w, conv_b, y_ws);
    softmax_kernel<<<1, 256, 0, stream>>>(y_ws, out);
}

// Round 12
// 225.669 us; speedup vs baseline: 1.3462x; 1.3462x over previous
//
#include <hip/hip_runtime.h>

#define TT 1024
#define KK 16
#define HH 20
#define NCELL 1024

typedef _Float16 f16;
typedef f16 f16x2 __attribute__((ext_vector_type(2)));

#define LOG2E 1.4426950408889634f

__device__ __forceinline__ float fdot2(f16x2 a, f16x2 b, float c) {
    // v_dot2_f32_f16: a.x*b.x + a.y*b.y + c, f32 accumulate.
    return __builtin_amdgcn_fdot2(a, b, c, false);
}
__device__ __forceinline__ float fast_rcp(float x) {
    return __builtin_amdgcn_rcpf(x);
}
// sigmoid in exp2 domain (x pre-scaled by log2e): rcp(1 + 2^-x).
__device__ __forceinline__ float sigm2(float x2) {
    return fast_rcp(1.0f + __builtin_amdgcn_exp2f(-x2));
}
// tanh of a TRUE-domain value.
__device__ __forceinline__ float tanh_fast(float x) {
    float e = __builtin_amdgcn_exp2f(x * (2.0f * LOG2E));
    return 1.0f - 2.0f * fast_rcp(e + 1.0f);
}
__device__ __forceinline__ float bcast(float v, int srclane) {
    return __int_as_float(__builtin_amdgcn_readlane(__float_as_int(v), srclane));
}
__device__ __forceinline__ unsigned bcast_u(unsigned v, int srclane) {
    return (unsigned)__builtin_amdgcn_readlane((int)v, srclane);
}

// Launder a pointer through a VGPR so the compiler cannot prove it uniform.
// Purpose: wave-uniform x addresses otherwise become SMEM s_loads; SMEM
// completes OUT-OF-ORDER, so the compiler must s_waitcnt lgkmcnt(0) before
// every consume — draining the refill issued the same step (~200 cy on the
// critical path, every step; the 4-deep prefetch did nothing). As VGPR
// addresses the loads go to vector memory (vmcnt, in-order) where partial
// vmcnt(N) waits make the prefetch actually span 4 steps.
__device__ __forceinline__ const float* vgpr_launder(const float* p) {
    asm("" : "+v"(p));
    return p;
}

struct F3 { float x, y, z; };

// ONE cell per wave (R10 structure): lanes 0..19 own hidden units; each lane
// holds all four gate rows of its unit, f16 pre-scaled by log2e (g-row by
// 2*log2e). Gate dots via v_dot2_f32_f16 in two 5-deep chains per row.
// h broadcast: own-h -> f16, neighbor pair via DPP quad_perm(xor1) + or,
// then 10 readlanes of packed f16x2 (uniform -> scalar operand of dot2).
// waves_per_eu(1,1): truthful (1024 blocks / 256 CU = 1 wave/SIMD).
__global__ __launch_bounds__(64)
__attribute__((amdgpu_waves_per_eu(1, 1)))
void lstm_kernel(
    const float* __restrict__ inp,    // [B][T][K][3]
    const float* __restrict__ W_ih,   // [K][80][3]
    const float* __restrict__ W_hh,   // [K][80][20]
    const float* __restrict__ b_ih,   // [K][80]
    const float* __restrict__ b_hh,   // [K][80]
    const float* __restrict__ w,      // [K*B+1]
    const float* __restrict__ conv_w, // [21]
    const float* __restrict__ conv_b, // [1]
    float* __restrict__ y_ws)         // [1024] pre-softmax y for rows 1..1024
{
    const int lane = threadIdx.x;
    const int cell = blockIdx.x;           // 0..1023
    const int k = cell >> 6;
    const int b = cell & 63;
    const int jj = lane & 31;
    const int j = (jj < HH) ? jj : (HH - 1);

    // Per-lane weights: 4 gate rows (i,f,g,o) of unit j, f16 pre-scaled.
    f16x2 Wh[4][10];     // W_hh pairs
    f16x2 Wx01[4];       // (Wi0, Wi1) pre-scaled
    f16x2 Wx2b[4];       // (Wi2, bias) pre-scaled  (dot with (x2, 1))
    {
        #pragma unroll
        for (int g = 0; g < 4; ++g) {
            const int r = k * 80 + g * HH + j;
            const float scale = LOG2E * ((g == 2) ? 2.0f : 1.0f);
            #pragma unroll
            for (int m = 0; m < 10; ++m) {
                Wh[g][m] = f16x2{(f16)(W_hh[r * HH + 2 * m] * scale),
                                 (f16)(W_hh[r * HH + 2 * m + 1] * scale)};
            }
            Wx01[g] = f16x2{(f16)(W_ih[r * 3 + 0] * scale),
                            (f16)(W_ih[r * 3 + 1] * scale)};
            Wx2b[g] = f16x2{(f16)(W_ih[r * 3 + 2] * scale),
                            (f16)((b_ih[r] + b_hh[r]) * scale)};
        }
    }

    float h_own = 0.0f, c_own = 0.0f;

    // Input base: inp[((b*T + t)*K + k)*3], stride 48 floats/t.
    // LAUNDERED into a VGPR address -> vector loads (vmcnt, in-order).
    const float* xb = vgpr_launder(inp + (b * TT * KK + k) * 3);
    F3 p0{xb[0 * 48], xb[0 * 48 + 1], xb[0 * 48 + 2]};
    F3 p1{xb[1 * 48], xb[1 * 48 + 1], xb[1 * 48 + 2]};
    F3 p2{xb[2 * 48], xb[2 * 48 + 1], xb[2 * 48 + 2]};
    F3 p3{xb[3 * 48], xb[3 * 48 + 1], xb[3 * 48 + 2]};

    auto step = [&](F3& p, int t) {
        // 1) h -> f16; pair with neighbor (DPP quad_perm xor1); 10 readlanes
        //    of packed f16x2 -> wave-uniform scalar operands for dot2.
        unsigned hb = (unsigned)__builtin_bit_cast(unsigned short, (f16)h_own);
        unsigned nb = (unsigned)__builtin_amdgcn_mov_dpp((int)hb, 0xB1, 0xF, 0xF, true);
        const unsigned packed = hb | (nb << 16);  // even lane 2m: (h[2m], h[2m+1])
        f16x2 hp[10];
        #pragma unroll
        for (int m = 0; m < 10; ++m)
            hp[m] = __builtin_bit_cast(f16x2, bcast_u(packed, 2 * m));

        const float x0 = p.x, x1 = p.y, x2 = p.z;
        // 2) refill p for step t+4 (vector loads; vmcnt spans 4 steps)
        {
            int tn = t + 4; tn = (tn < TT) ? tn : (TT - 1);
            const float* q = xb + tn * (KK * 3);
            p.x = q[0]; p.y = q[1]; p.z = q[2];
        }
        // 3) x packed to f16 (off the h critical path)
        const f16x2 xp01 = f16x2{(f16)x0, (f16)x1};
        const f16x2 xp2b = f16x2{(f16)x2, (f16)1.0f};
        // 4) gate dots: per row, xproj (2 dot2) + 2 chains of 5 dot2
        float a0, a1, a2, a3;
        {
            float q00 = fdot2(Wx01[0], xp01, fdot2(Wx2b[0], xp2b, 0.0f)), q01 = 0.f;
            float q10 = fdot2(Wx01[1], xp01, fdot2(Wx2b[1], xp2b, 0.0f)), q11 = 0.f;
            float q20 = fdot2(Wx01[2], xp01, fdot2(Wx2b[2], xp2b, 0.0f)), q21 = 0.f;
            float q30 = fdot2(Wx01[3], xp01, fdot2(Wx2b[3], xp2b, 0.0f)), q31 = 0.f;
            #pragma unroll
            for (int m = 0; m < 5; ++m) {
                q00 = fdot2(Wh[0][m], hp[m], q00);
                q10 = fdot2(Wh[1][m], hp[m], q10);
                q20 = fdot2(Wh[2][m], hp[m], q20);
                q30 = fdot2(Wh[3][m], hp[m], q30);
                q01 = fdot2(Wh[0][m + 5], hp[m + 5], q01);
                q11 = fdot2(Wh[1][m + 5], hp[m + 5], q11);
                q21 = fdot2(Wh[2][m + 5], hp[m + 5], q21);
                q31 = fdot2(Wh[3][m + 5], hp[m + 5], q31);
            }
            a0 = q00 + q01; a1 = q10 + q11; a2 = q20 + q21; a3 = q30 + q31;
        }
        // 5) activations: 4 parallel chains (exp2 domain)
        const float sI = sigm2(a0);
        const float sF = sigm2(a1);
        const float tG = sigm2(a2) * 2.0f - 1.0f;   // tanh(g)
        const float sO = sigm2(a3);
        // 6) state update (lane-local)
        c_own = sF * c_own + sI * tG;
        h_own = sO * tanh_fast(c_own);
    };

    for (int tb = 0; tb < TT; tb += 4) {
        step(p0, tb + 0);
        step(p1, tb + 1);
        step(p2, tb + 2);
        step(p3, tb + 3);
    }

    // Epilogue: final h via readlane (f32), y = tanh(feat . conv_w + conv_b)
    float acc = conv_b[0];
    #pragma unroll
    for (int hh = 0; hh < HH; ++hh) acc += conv_w[hh] * bcast(h_own, hh);
    acc += conv_w[HH] * w[1 + cell];
    if (lane == 0) y_ws[cell] = tanh_fast(acc);
}

// Softmax over [1, y_0 .. y_1023] -> out[1025]
__global__ __launch_bounds__(256) void softmax_kernel(
    const float* __restrict__ y_ws, float* __restrict__ out)
{
    __shared__ float red[4];
    const int tid = threadIdx.x;
    float vals[5];
    float local = 0.0f;
    #pragma unroll
    for (int it = 0; it < 5; ++it) {
        const int idx = tid + it * 256;
        if (idx < NCELL + 1) {
            const float y = (idx == 0) ? 1.0f : y_ws[idx - 1];
            const float e = __expf(y);
            vals[it] = e;
            local += e;
        } else {
            vals[it] = 0.0f;
        }
    }
    #pragma unroll
    for (int off = 32; off > 0; off >>= 1) local += __shfl_down(local, off, 64);
    if ((tid & 63) == 0) red[tid >> 6] = local;
    __syncthreads();
    const float total = red[0] + red[1] + red[2] + red[3];
    const float inv = 1.0f / total;
    #pragma unroll
    for (int it = 0; it < 5; ++it) {
        const int idx = tid + it * 256;
        if (idx < NCELL + 1) out[idx] = vals[it] * inv;
    }
}

extern "C" void kernel_launch(void* const* d_in, const int* in_sizes, int n_in,
                              void* d_out, int out_size, void* d_ws, size_t ws_size,
                              hipStream_t stream) {
    const float* inp    = (const float*)d_in[0];
    const float* w      = (const float*)d_in[1];
    const float* W_ih   = (const float*)d_in[2];
    const float* W_hh   = (const float*)d_in[3];
    const float* b_ih   = (const float*)d_in[4];
    const float* b_hh   = (const float*)d_in[5];
    const float* conv_w = (const float*)d_in[6];
    const float* conv_b = (const float*)d_in[7];
    float* out  = (float*)d_out;
    float* y_ws = (float*)d_ws;

    lstm_kernel<<<NCELL, 64, 0, stream>>>(inp, W_ih, W_hh, b_ih, b_hh, w,
                                          conv_w, conv_b, y_ws);
    softmax_kernel<<<1, 256, 0, stream>>>(y_ws, out);
}

// Round 13
// 162.504 us; speedup vs baseline: 1.8695x; 1.3887x over previous
//
#include <hip/hip_runtime.h>

#define TT 1024
#define KK 16
#define HH 20
#define NCELL 1024

typedef _Float16 f16;
typedef f16 f16x2 __attribute__((ext_vector_type(2)));

#define LOG2E 1.4426950408889634f

__device__ __forceinline__ float fdot2(f16x2 a, f16x2 b, float c) {
    // v_dot2_f32_f16: a.x*b.x + a.y*b.y + c, f32 accumulate.
    return __builtin_amdgcn_fdot2(a, b, c, false);
}
__device__ __forceinline__ float fast_rcp(float x) {
    return __builtin_amdgcn_rcpf(x);
}
// sigmoid in exp2 domain (x pre-scaled by log2e): rcp(1 + 2^-x).
__device__ __forceinline__ float sigm2(float x2) {
    return fast_rcp(1.0f + __builtin_amdgcn_exp2f(-x2));
}
// tanh of a TRUE-domain value.
__device__ __forceinline__ float tanh_fast(float x) {
    float e = __builtin_amdgcn_exp2f(x * (2.0f * LOG2E));
    return 1.0f - 2.0f * fast_rcp(e + 1.0f);
}
__device__ __forceinline__ float bcast(float v, int srclane) {
    return __int_as_float(__builtin_amdgcn_readlane(__float_as_int(v), srclane));
}
__device__ __forceinline__ unsigned bcast_u(unsigned v, int srclane) {
    return (unsigned)__builtin_amdgcn_readlane((int)v, srclane);
}

// v_permlane32_swap_b32 a,b with a=b=v: a = v's low-half value in ALL lanes,
// b = v's high-half value in ALL lanes.
__device__ __forceinline__ void half_bcast(float v, float& from_lo, float& from_hi) {
    float a = v, b = v;
    asm("v_permlane32_swap_b32 %0, %1" : "+v"(a), "+v"(b));
    from_lo = a; from_hi = b;
}

// Launder the input pointer into a VGPR so the compiler cannot prove it
// uniform. Wave-uniform x addresses become SMEM s_loads; SMEM completes
// OUT-OF-ORDER, so every x consume needs s_waitcnt lgkmcnt(0), which drains
// the refill issued only ONE step (~434cy) earlier against an HBM-latency
// (~600-900cy) load -> ~200-400cy stall per step. Vector loads (vmcnt) are
// in-order: partial vmcnt(N) waits let the 4-step prefetch really span 4
// steps. (R12 tested this confounded with a structure change; this is the
// clean A/B on the R10 winner.)
__device__ __forceinline__ const float* vgpr_launder(const float* p) {
    asm("" : "+v"(p));
    return p;
}

struct F3 { float x, y, z; };

// R10 structure, verbatim: ONE cell per wave, gates split across wave halves:
//   lanes 0..31  (unit j=min(lane&31,19)): gate rows i (j),    f (20+j)
//   lanes 32..63:                          gate rows g (40+j), o (60+j)
// Recurrent weights f16 pre-scaled by log2e (g-row by 2*log2e) -> every
// activation is rcp(1+exp2(-x)). Gate dots via v_dot2_f32_f16, two 5-deep
// chains per row. h broadcast: own-h -> f16, neighbor via DPP quad_perm
// xor1 + or, then 10 readlanes of packed f16x2. Cross-half recombine via
// v_permlane32_swap_b32. waves_per_eu(1,1): truthful (1 wave/SIMD).
__global__ __launch_bounds__(64)
__attribute__((amdgpu_waves_per_eu(1, 1)))
void lstm_kernel(
    const float* __restrict__ inp,    // [B][T][K][3]
    const float* __restrict__ W_ih,   // [K][80][3]
    const float* __restrict__ W_hh,   // [K][80][20]
    const float* __restrict__ b_ih,   // [K][80]
    const float* __restrict__ b_hh,   // [K][80]
    const float* __restrict__ w,      // [K*B+1]
    const float* __restrict__ conv_w, // [21]
    const float* __restrict__ conv_b, // [1]
    float* __restrict__ y_ws)         // [1024] pre-softmax y for rows 1..1024
{
    const int lane = threadIdx.x;
    const int cell = blockIdx.x;           // 0..1023
    const int k = cell >> 6;
    const int b = cell & 63;
    const int half = lane >> 5;            // 0: rows i,f   1: rows g,o
    const int jj = lane & 31;
    const int j = (jj < HH) ? jj : (HH - 1);

    // Per-lane weights: row A = (half?g:i), row B = (half?o:f), f16 pre-scaled.
    f16x2 WpA[10], WpB[10];
    float WiA[3], WiB[3];
    float biasA, biasB;
    {
        const int rA = k * 80 + (half * 2) * HH + j;
        const int rB = rA + HH;
        const float scaleA = LOG2E * (half ? 2.0f : 1.0f);  // g-row: sigma(2x)
        const float scaleB = LOG2E;
        #pragma unroll
        for (int m = 0; m < 10; ++m) {
            WpA[m] = f16x2{(f16)(W_hh[rA * HH + 2 * m] * scaleA),
                           (f16)(W_hh[rA * HH + 2 * m + 1] * scaleA)};
            WpB[m] = f16x2{(f16)(W_hh[rB * HH + 2 * m] * scaleB),
                           (f16)(W_hh[rB * HH + 2 * m + 1] * scaleB)};
        }
        #pragma unroll
        for (int i = 0; i < 3; ++i) {
            WiA[i] = W_ih[rA * 3 + i] * scaleA;
            WiB[i] = W_ih[rB * 3 + i] * scaleB;
        }
        biasA = (b_ih[rA] + b_hh[rA]) * scaleA;
        biasB = (b_ih[rB] + b_hh[rB]) * scaleB;
    }
    // A-row post-activation affine: half0 identity; half1 tanh = 2*sigma(2x)-1.
    const float mA = half ? 2.0f : 1.0f;
    const float bA = half ? -1.0f : 0.0f;

    float h_own = 0.0f, c_own = 0.0f;

    // Input base: inp[((b*T + t)*K + k)*3], stride 48 floats/t.
    // LAUNDERED -> vector loads (vmcnt, in-order partial waits).
    const float* xb = vgpr_launder(inp + (b * TT * KK + k) * 3);
    F3 p0{xb[0 * 48], xb[0 * 48 + 1], xb[0 * 48 + 2]};
    F3 p1{xb[1 * 48], xb[1 * 48 + 1], xb[1 * 48 + 2]};
    F3 p2{xb[2 * 48], xb[2 * 48 + 1], xb[2 * 48 + 2]};
    F3 p3{xb[3 * 48], xb[3 * 48 + 1], xb[3 * 48 + 2]};

    auto step = [&](F3& p, int t) {
        // 1) h -> f16; pair with neighbor (DPP quad_perm xor1); 10 readlanes
        //    of packed f16x2 -> wave-uniform scalar operands for dot2.
        unsigned hb = (unsigned)__builtin_bit_cast(unsigned short, (f16)h_own);
        unsigned nb = (unsigned)__builtin_amdgcn_mov_dpp((int)hb, 0xB1, 0xF, 0xF, true);
        const unsigned packed = hb | (nb << 16);  // even lane 2m: (h[2m], h[2m+1])
        f16x2 hp[10];
        #pragma unroll
        for (int m = 0; m < 10; ++m)
            hp[m] = __builtin_bit_cast(f16x2, bcast_u(packed, 2 * m));

        const float x0 = p.x, x1 = p.y, x2 = p.z;
        // 2) refill p for step t+4 (vector loads; vmcnt spans 4 steps)
        {
            int tn = t + 4; tn = (tn < TT) ? tn : (TT - 1);
            const float* q = xb + tn * (KK * 3);
            p.x = q[0]; p.y = q[1]; p.z = q[2];
        }
        // 3) x-projection + bias (f32, off the h critical path)
        const float eA = biasA + WiA[0] * x0 + WiA[1] * x1 + WiA[2] * x2;
        const float eB = biasB + WiB[0] * x0 + WiB[1] * x1 + WiB[2] * x2;
        // 4) gate dots: 10 dot2 per row, split into two 5-deep chains
        float pA0 = eA, pA1 = 0.f, pB0 = eB, pB1 = 0.f;
        #pragma unroll
        for (int m = 0; m < 5; ++m) {
            pA0 = fdot2(WpA[m], hp[m], pA0);
            pB0 = fdot2(WpB[m], hp[m], pB0);
            pA1 = fdot2(WpA[m + 5], hp[m + 5], pA1);
            pB1 = fdot2(WpB[m + 5], hp[m + 5], pB1);
        }
        const float gA = pA0 + pA1;     // half0: i-pre   half1: g-pre (scaled)
        const float gB = pB0 + pB1;     // half0: f-pre   half1: o-pre (scaled)
        // 5) activations (exp2 domain, no pre-muls)
        const float uA = sigm2(gA);
        const float actA = uA * mA + bA;       // sigma(i) or tanh(g)
        const float actB = sigm2(gB);          // sigma(f) or sigma(o)
        // 6) cross-half exchange: all lanes get sI, tG, sF, sO for unit jj
        float sI, tG, sF, sO;
        half_bcast(actA, sI, tG);
        half_bcast(actB, sF, sO);
        // 7) state update (h_own valid in lanes 0..19, shadowed in 32..51)
        c_own = sF * c_own + sI * tG;
        h_own = sO * tanh_fast(c_own);
    };

    for (int tb = 0; tb < TT; tb += 4) {
        step(p0, tb + 0);
        step(p1, tb + 1);
        step(p2, tb + 2);
        step(p3, tb + 3);
    }

    // Epilogue: final h via readlane (f32), y = tanh(feat . conv_w + conv_b)
    float acc = conv_b[0];
    #pragma unroll
    for (int hh = 0; hh < HH; ++hh) acc += conv_w[hh] * bcast(h_own, hh);
    acc += conv_w[HH] * w[1 + cell];
    if (lane == 0) y_ws[cell] = tanh_fast(acc);
}

// Softmax over [1, y_0 .. y_1023] -> out[1025]
__global__ __launch_bounds__(256) void softmax_kernel(
    const float* __restrict__ y_ws, float* __restrict__ out)
{
    __shared__ float red[4];
    const int tid = threadIdx.x;
    float vals[5];
    float local = 0.0f;
    #pragma unroll
    for (int it = 0; it < 5; ++it) {
        const int idx = tid + it * 256;
        if (idx < NCELL + 1) {
            const float y = (idx == 0) ? 1.0f : y_ws[idx - 1];
            const float e = __expf(y);
            vals[it] = e;
            local += e;
        } else {
            vals[it] = 0.0f;
        }
    }
    #pragma unroll
    for (int off = 32; off > 0; off >>= 1) local += __shfl_down(local, off, 64);
    if ((tid & 63) == 0) red[tid >> 6] = local;
    __syncthreads();
    const float total = red[0] + red[1] + red[2] + red[3];
    const float inv = 1.0f / total;
    #pragma unroll
    for (int it = 0; it < 5; ++it) {
        const int idx = tid + it * 256;
        if (idx < NCELL + 1) out[idx] = vals[it] * inv;
    }
}

extern "C" void kernel_launch(void* const* d_in, const int* in_sizes, int n_in,
                              void* d_out, int out_size, void* d_ws, size_t ws_size,
                              hipStream_t stream) {
    const float* inp    = (const float*)d_in[0];
    const float* w      = (const float*)d_in[1];
    const float* W_ih   = (const float*)d_in[2];
    const float* W_hh   = (const float*)d_in[3];
    const float* b_ih   = (const float*)d_in[4];
    const float* b_hh   = (const float*)d_in[5];
    const float* conv_w = (const float*)d_in[6];
    const float* conv_b = (const float*)d_in[7];
    float* out  = (float*)d_out;
    float* y_ws = (float*)d_ws;

    lstm_kernel<<<NCELL, 64, 0, stream>>>(inp, W_ih, W_hh, b_ih, b_hh, w,
                                          conv_w, conv_b, y_ws);
    softmax_kernel<<<1, 256, 0, stream>>>(y_ws, out);
}

// Round 14
// 162.176 us; speedup vs baseline: 1.8733x; 1.0020x over previous
//
#include <hip/hip_runtime.h>

#define TT 1024
#define KK 16
#define HH 20
#define NCELL 1024

typedef _Float16 f16;
typedef f16 f16x2 __attribute__((ext_vector_type(2)));

#define LOG2E 1.4426950408889634f

__device__ __forceinline__ float fdot2(f16x2 a, f16x2 b, float c) {
    // v_dot2_f32_f16: a.x*b.x + a.y*b.y + c, f32 accumulate.
    return __builtin_amdgcn_fdot2(a, b, c, false);
}
__device__ __forceinline__ float fast_rcp(float x) {
    return __builtin_amdgcn_rcpf(x);
}
// sigmoid in exp2 domain (x pre-scaled by log2e): rcp(1 + 2^-x).
__device__ __forceinline__ float sigm2(float x2) {
    return fast_rcp(1.0f + __builtin_amdgcn_exp2f(-x2));
}
// tanh of a TRUE-domain value.
__device__ __forceinline__ float tanh_fast(float x) {
    float e = __builtin_amdgcn_exp2f(x * (2.0f * LOG2E));
    return 1.0f - 2.0f * fast_rcp(e + 1.0f);
}
__device__ __forceinline__ float bcast(float v, int srclane) {
    return __int_as_float(__builtin_amdgcn_readlane(__float_as_int(v), srclane));
}
__device__ __forceinline__ unsigned bcast_u(unsigned v, int srclane) {
    return (unsigned)__builtin_amdgcn_readlane((int)v, srclane);
}

// v_permlane32_swap_b32 a,b with a=b=v: a = v's low-half value in ALL lanes,
// b = v's high-half value in ALL lanes.
__device__ __forceinline__ void half_bcast(float v, float& from_lo, float& from_hi) {
    float a = v, b = v;
    asm("v_permlane32_swap_b32 %0, %1" : "+v"(a), "+v"(b));
    from_lo = a; from_hi = b;
}

// R13 + LDS-staged input. R13's launder proved the x-path stall: vector loads
// helped (185->162.5) but cold/warm dispatch spread (240 vs 162us) shows the
// vmcnt waits still leak latency into every step. Fix: stage the cell's whole
// input trace into LDS once (8KB: per t, f16-packed (x0,x1)|(x2,1.0) with the
// conversion done at staging), then the per-step x-path is ONE ds_read_b64.
// DS ops complete in-order among themselves -> partial lgkmcnt(N) waits
// genuinely span the 4-step rotation; no vmcnt in the steady loop.
//
// Structure otherwise R13: ONE cell per wave, gates split across halves
// (lanes 0..31: rows i,f of unit j=min(lane&31,19); lanes 32..63: rows g,o);
// f16 weights pre-scaled by log2e (g-row 2x); dot2 in two 5-deep chains;
// h broadcast = cvt + DPP xor1 + or, 10 readlanes of packed pairs;
// recombine via v_permlane32_swap_b32; exp2-domain activations.
// waves_per_eu(1,1): truthful (1024 blocks / 256 CU = 1 wave/SIMD).
__global__ __launch_bounds__(64)
__attribute__((amdgpu_waves_per_eu(1, 1)))
void lstm_kernel(
    const float* __restrict__ inp,    // [B][T][K][3]
    const float* __restrict__ W_ih,   // [K][80][3]
    const float* __restrict__ W_hh,   // [K][80][20]
    const float* __restrict__ b_ih,   // [K][80]
    const float* __restrict__ b_hh,   // [K][80]
    const float* __restrict__ w,      // [K*B+1]
    const float* __restrict__ conv_w, // [21]
    const float* __restrict__ conv_b, // [1]
    float* __restrict__ y_ws)         // [1024] pre-softmax y for rows 1..1024
{
    __shared__ unsigned long long xs[TT];  // 8KB: lo32=(x0,x1) f16x2, hi32=(x2,1)

    const int lane = threadIdx.x;
    const int cell = blockIdx.x;           // 0..1023
    const int k = cell >> 6;
    const int b = cell & 63;
    const int half = lane >> 5;            // 0: rows i,f   1: rows g,o
    const int jj = lane & 31;
    const int j = (jj < HH) ? jj : (HH - 1);

    // ---- Stage input trace for this cell into LDS (once) ----
    {
        const float* xbg = inp + (b * TT * KK + k) * 3;
        for (int t = lane; t < TT; t += 64) {
            const float* q = xbg + t * (KK * 3);
            const f16x2 lo = f16x2{(f16)q[0], (f16)q[1]};
            const f16x2 hi = f16x2{(f16)q[2], (f16)1.0f};
            xs[t] = ((unsigned long long)__builtin_bit_cast(unsigned, hi) << 32)
                  | __builtin_bit_cast(unsigned, lo);
        }
    }

    // Per-lane weights: row A = (half?g:i), row B = (half?o:f), f16 pre-scaled.
    f16x2 WhA[10], WhB[10];
    f16x2 WxA01, WxA2b, WxB01, WxB2b;   // xproj weights; bias folded into *2b
    {
        const int rA = k * 80 + (half * 2) * HH + j;
        const int rB = rA + HH;
        const float scaleA = LOG2E * (half ? 2.0f : 1.0f);  // g-row: sigma(2x)
        const float scaleB = LOG2E;
        #pragma unroll
        for (int m = 0; m < 10; ++m) {
            WhA[m] = f16x2{(f16)(W_hh[rA * HH + 2 * m] * scaleA),
                           (f16)(W_hh[rA * HH + 2 * m + 1] * scaleA)};
            WhB[m] = f16x2{(f16)(W_hh[rB * HH + 2 * m] * scaleB),
                           (f16)(W_hh[rB * HH + 2 * m + 1] * scaleB)};
        }
        WxA01 = f16x2{(f16)(W_ih[rA * 3 + 0] * scaleA), (f16)(W_ih[rA * 3 + 1] * scaleA)};
        WxB01 = f16x2{(f16)(W_ih[rB * 3 + 0] * scaleB), (f16)(W_ih[rB * 3 + 1] * scaleB)};
        WxA2b = f16x2{(f16)(W_ih[rA * 3 + 2] * scaleA),
                      (f16)((b_ih[rA] + b_hh[rA]) * scaleA)};
        WxB2b = f16x2{(f16)(W_ih[rB * 3 + 2] * scaleB),
                      (f16)((b_ih[rB] + b_hh[rB]) * scaleB)};
    }
    // A-row post-activation affine: half0 identity; half1 tanh = 2*sigma(2x)-1.
    const float mA = half ? 2.0f : 1.0f;
    const float bA = half ? -1.0f : 0.0f;

    float h_own = 0.0f, c_own = 0.0f;

    __syncthreads();   // staging visible

    // 4-deep rotating x registers from LDS.
    unsigned long long xq0 = xs[0], xq1 = xs[1], xq2 = xs[2], xq3 = xs[3];

    auto step = [&](unsigned long long& xq, int t) {
        // 1) h -> f16; pair with neighbor (DPP quad_perm xor1); 10 readlanes
        //    of packed f16x2 -> wave-uniform scalar operands for dot2.
        unsigned hb = (unsigned)__builtin_bit_cast(unsigned short, (f16)h_own);
        unsigned nb = (unsigned)__builtin_amdgcn_mov_dpp((int)hb, 0xB1, 0xF, 0xF, true);
        const unsigned packed = hb | (nb << 16);  // even lane 2m: (h[2m], h[2m+1])
        f16x2 hp[10];
        #pragma unroll
        for (int m = 0; m < 10; ++m)
            hp[m] = __builtin_bit_cast(f16x2, bcast_u(packed, 2 * m));

        const f16x2 xp01 = __builtin_bit_cast(f16x2, (unsigned)xq);
        const f16x2 xp2b = __builtin_bit_cast(f16x2, (unsigned)(xq >> 32));
        // 2) refill xq for step t+4 (ds_read_b64; lgkmcnt spans 4 steps)
        {
            int tn = t + 4; tn = (tn < TT) ? tn : (TT - 1);
            xq = xs[tn];
        }
        // 3) x-projection (2 dot2 per row, bias folded into the (x2,1) dot)
        const float eA = fdot2(WxA01, xp01, fdot2(WxA2b, xp2b, 0.0f));
        const float eB = fdot2(WxB01, xp01, fdot2(WxB2b, xp2b, 0.0f));
        // 4) gate dots: 10 dot2 per row, two 5-deep chains
        float pA0 = eA, pA1 = 0.f, pB0 = eB, pB1 = 0.f;
        #pragma unroll
        for (int m = 0; m < 5; ++m) {
            pA0 = fdot2(WhA[m], hp[m], pA0);
            pB0 = fdot2(WhB[m], hp[m], pB0);
            pA1 = fdot2(WhA[m + 5], hp[m + 5], pA1);
            pB1 = fdot2(WhB[m + 5], hp[m + 5], pB1);
        }
        const float gA = pA0 + pA1;     // half0: i-pre   half1: g-pre (scaled)
        const float gB = pB0 + pB1;     // half0: f-pre   half1: o-pre (scaled)
        // 5) activations (exp2 domain)
        const float uA = sigm2(gA);
        const float actA = uA * mA + bA;       // sigma(i) or tanh(g)
        const float actB = sigm2(gB);          // sigma(f) or sigma(o)
        // 6) cross-half exchange: all lanes get sI, tG, sF, sO for unit jj
        float sI, tG, sF, sO;
        half_bcast(actA, sI, tG);
        half_bcast(actB, sF, sO);
        // 7) state update (h_own valid in lanes 0..19, shadowed in 32..51)
        c_own = sF * c_own + sI * tG;
        h_own = sO * tanh_fast(c_own);
    };

    for (int tb = 0; tb < TT; tb += 4) {
        step(xq0, tb + 0);
        step(xq1, tb + 1);
        step(xq2, tb + 2);
        step(xq3, tb + 3);
    }

    // Epilogue: final h via readlane (f32), y = tanh(feat . conv_w + conv_b)
    float acc = conv_b[0];
    #pragma unroll
    for (int hh = 0; hh < HH; ++hh) acc += conv_w[hh] * bcast(h_own, hh);
    acc += conv_w[HH] * w[1 + cell];
    if (lane == 0) y_ws[cell] = tanh_fast(acc);
}

// Softmax over [1, y_0 .. y_1023] -> out[1025]
__global__ __launch_bounds__(256) void softmax_kernel(
    const float* __restrict__ y_ws, float* __restrict__ out)
{
    __shared__ float red[4];
    const int tid = threadIdx.x;
    float vals[5];
    float local = 0.0f;
    #pragma unroll
    for (int it = 0; it < 5; ++it) {
        const int idx = tid + it * 256;
        if (idx < NCELL + 1) {
            const float y = (idx == 0) ? 1.0f : y_ws[idx - 1];
            const float e = __expf(y);
            vals[it] = e;
            local += e;
        } else {
            vals[it] = 0.0f;
        }
    }
    #pragma unroll
    for (int off = 32; off > 0; off >>= 1) local += __shfl_down(local, off, 64);
    if ((tid & 63) == 0) red[tid >> 6] = local;
    __syncthreads();
    const float total = red[0] + red[1] + red[2] + red[3];
    const float inv = 1.0f / total;
    #pragma unroll
    for (int it = 0; it < 5; ++it) {
        const int idx = tid + it * 256;
        if (idx < NCELL + 1) out[idx] = vals[it] * inv;
    }
}

extern "C" void kernel_launch(void* const* d_in, const int* in_sizes, int n_in,
                              void* d_out, int out_size, void* d_ws, size_t ws_size,
                              hipStream_t stream) {
    const float* inp    = (const float*)d_in[0];
    const float* w      = (const float*)d_in[1];
    const float* W_ih   = (const float*)d_in[2];
    const float* W_hh   = (const float*)d_in[3];
    const float* b_ih   = (const float*)d_in[4];
    const float* b_hh   = (const float*)d_in[5];
    const float* conv_w = (const float*)d_in[6];
    const float* conv_b = (const float*)d_in[7];
    float* out  = (float*)d_out;
    float* y_ws = (float*)d_ws;

    lstm_kernel<<<NCELL, 64, 0, stream>>>(inp, W_ih, W_hh, b_ih, b_hh, w,
                                          conv_w, conv_b, y_ws);
    softmax_kernel<<<1, 256, 0, stream>>>(y_ws, out);
}

// Round 16
// 151.374 us; speedup vs baseline: 2.0070x; 1.0714x over previous
//
#include <hip/hip_runtime.h>

#define TT 1024
#define KK 16
#define HH 20
#define NCELL 1024

typedef _Float16 f16;
typedef f16 f16x2 __attribute__((ext_vector_type(2)));
typedef __fp16 fp16x2_raw __attribute__((ext_vector_type(2)));  // cvt_pkrtz return type

#define LOG2E 1.4426950408889634f

__device__ __forceinline__ float fdot2(f16x2 a, f16x2 b, float c) {
    // v_dot2_f32_f16: a.x*b.x + a.y*b.y + c, f32 accumulate.
    return __builtin_amdgcn_fdot2(a, b, c, false);
}
__device__ __forceinline__ float fast_rcp(float x) {
    return __builtin_amdgcn_rcpf(x);
}
// sigmoid in exp2 domain (x pre-scaled by log2e): rcp(1 + 2^-x).
__device__ __forceinline__ float sigm2(float x2) {
    return fast_rcp(1.0f + __builtin_amdgcn_exp2f(-x2));
}
// tanh of a TRUE-domain value.
__device__ __forceinline__ float tanh_fast(float x) {
    float e = __builtin_amdgcn_exp2f(x * (2.0f * LOG2E));
    return 1.0f - 2.0f * fast_rcp(e + 1.0f);
}
__device__ __forceinline__ float bcast(float v, int srclane) {
    return __int_as_float(__builtin_amdgcn_readlane(__float_as_int(v), srclane));
}
__device__ __forceinline__ unsigned bcast_u(unsigned v, int srclane) {
    return (unsigned)__builtin_amdgcn_readlane((int)v, srclane);
}

// v_permlane32_swap_b32 a,b with a=b=v: a = v's low-half value in ALL lanes,
// b = v's high-half value in ALL lanes.
__device__ __forceinline__ void half_bcast(float v, float& from_lo, float& from_hi) {
    float a = v, b = v;
    asm("v_permlane32_swap_b32 %0, %1" : "+v"(a), "+v"(b));
    from_lo = a; from_hi = b;
}

// R14 + issue shaves (R14 post-mortem: x-path exonerated — staging flattened
// dispatch variance but not wall; step = ~274cy VALU issue + chain):
//  1. xs padded to TT+4 -> no per-step clamp (v_min gone); group-top refill:
//     4 ds_read_b64 with immediate offsets, consumed as register renames at
//     group end (lgkmcnt satisfied ~1500cy after issue). ~4 VALU/step saved.
//  2. h-pack via DPP-xor1 on f32 + ONE v_cvt_pkrtz_f16_f32(h, h_nb) — 2 dep
//     ops instead of cvt+dpp+or (3) at the head of the serial chain.
//     (R15 fix: bit_cast the builtin's __fp16-vector return to our f16x2.)
//
// Structure otherwise R13/R14: ONE cell per wave, gates split across halves
// (lanes 0..31: rows i,f of unit j=min(lane&31,19); lanes 32..63: rows g,o);
// f16 weights pre-scaled by log2e (g-row 2x); dot2 in two 5-deep chains;
// 10 readlanes of packed h pairs; recombine via v_permlane32_swap_b32;
// exp2-domain activations. waves_per_eu(1,1): truthful (1 wave/SIMD).
__global__ __launch_bounds__(64)
__attribute__((amdgpu_waves_per_eu(1, 1)))
void lstm_kernel(
    const float* __restrict__ inp,    // [B][T][K][3]
    const float* __restrict__ W_ih,   // [K][80][3]
    const float* __restrict__ W_hh,   // [K][80][20]
    const float* __restrict__ b_ih,   // [K][80]
    const float* __restrict__ b_hh,   // [K][80]
    const float* __restrict__ w,      // [K*B+1]
    const float* __restrict__ conv_w, // [21]
    const float* __restrict__ conv_b, // [1]
    float* __restrict__ y_ws)         // [1024] pre-softmax y for rows 1..1024
{
    __shared__ unsigned long long xs[TT + 4];  // lo32=(x0,x1) f16x2, hi32=(x2,1)

    const int lane = threadIdx.x;
    const int cell = blockIdx.x;           // 0..1023
    const int k = cell >> 6;
    const int b = cell & 63;
    const int half = lane >> 5;            // 0: rows i,f   1: rows g,o
    const int jj = lane & 31;
    const int j = (jj < HH) ? jj : (HH - 1);

    // ---- Stage input trace for this cell into LDS (once; tail padded) ----
    {
        const float* xbg = inp + (b * TT * KK + k) * 3;
        for (int i = lane; i < TT + 4; i += 64) {
            const int t = (i < TT) ? i : (TT - 1);
            const float* q = xbg + t * (KK * 3);
            const f16x2 lo = f16x2{(f16)q[0], (f16)q[1]};
            const f16x2 hi = f16x2{(f16)q[2], (f16)1.0f};
            xs[i] = ((unsigned long long)__builtin_bit_cast(unsigned, hi) << 32)
                  | __builtin_bit_cast(unsigned, lo);
        }
    }

    // Per-lane weights: row A = (half?g:i), row B = (half?o:f), f16 pre-scaled.
    f16x2 WhA[10], WhB[10];
    f16x2 WxA01, WxA2b, WxB01, WxB2b;   // xproj weights; bias folded into *2b
    {
        const int rA = k * 80 + (half * 2) * HH + j;
        const int rB = rA + HH;
        const float scaleA = LOG2E * (half ? 2.0f : 1.0f);  // g-row: sigma(2x)
        const float scaleB = LOG2E;
        #pragma unroll
        for (int m = 0; m < 10; ++m) {
            WhA[m] = f16x2{(f16)(W_hh[rA * HH + 2 * m] * scaleA),
                           (f16)(W_hh[rA * HH + 2 * m + 1] * scaleA)};
            WhB[m] = f16x2{(f16)(W_hh[rB * HH + 2 * m] * scaleB),
                           (f16)(W_hh[rB * HH + 2 * m + 1] * scaleB)};
        }
        WxA01 = f16x2{(f16)(W_ih[rA * 3 + 0] * scaleA), (f16)(W_ih[rA * 3 + 1] * scaleA)};
        WxB01 = f16x2{(f16)(W_ih[rB * 3 + 0] * scaleB), (f16)(W_ih[rB * 3 + 1] * scaleB)};
        WxA2b = f16x2{(f16)(W_ih[rA * 3 + 2] * scaleA),
                      (f16)((b_ih[rA] + b_hh[rA]) * scaleA)};
        WxB2b = f16x2{(f16)(W_ih[rB * 3 + 2] * scaleB),
                      (f16)((b_ih[rB] + b_hh[rB]) * scaleB)};
    }
    // A-row post-activation affine: half0 identity; half1 tanh = 2*sigma(2x)-1.
    const float mA = half ? 2.0f : 1.0f;
    const float bA = half ? -1.0f : 0.0f;

    float h_own = 0.0f, c_own = 0.0f;

    __syncthreads();   // staging visible

    auto step = [&](const unsigned long long xq) {
        // 1) h-pack: neighbor f32 via DPP xor1, ONE cvt_pkrtz -> (h2m, h2m+1);
        //    10 readlanes of packed f16x2 -> wave-uniform operands for dot2.
        const unsigned hb32 = __float_as_uint(h_own);
        const unsigned nb32 =
            (unsigned)__builtin_amdgcn_mov_dpp((int)hb32, 0xB1, 0xF, 0xF, true);
        const fp16x2_raw hpk_raw =
            __builtin_amdgcn_cvt_pkrtz(h_own, __uint_as_float(nb32));
        const unsigned packed = __builtin_bit_cast(unsigned, hpk_raw);
        f16x2 hp[10];
        #pragma unroll
        for (int m = 0; m < 10; ++m)
            hp[m] = __builtin_bit_cast(f16x2, bcast_u(packed, 2 * m));

        const f16x2 xp01 = __builtin_bit_cast(f16x2, (unsigned)xq);
        const f16x2 xp2b = __builtin_bit_cast(f16x2, (unsigned)(xq >> 32));
        // 2) x-projection (2 dot2 per row, bias folded into the (x2,1) dot)
        const float eA = fdot2(WxA01, xp01, fdot2(WxA2b, xp2b, 0.0f));
        const float eB = fdot2(WxB01, xp01, fdot2(WxB2b, xp2b, 0.0f));
        // 3) gate dots: 10 dot2 per row, two 5-deep chains
        float pA0 = eA, pA1 = 0.f, pB0 = eB, pB1 = 0.f;
        #pragma unroll
        for (int m = 0; m < 5; ++m) {
            pA0 = fdot2(WhA[m], hp[m], pA0);
            pB0 = fdot2(WhB[m], hp[m], pB0);
            pA1 = fdot2(WhA[m + 5], hp[m + 5], pA1);
            pB1 = fdot2(WhB[m + 5], hp[m + 5], pB1);
        }
        const float gA = pA0 + pA1;     // half0: i-pre   half1: g-pre (scaled)
        const float gB = pB0 + pB1;     // half0: f-pre   half1: o-pre (scaled)
        // 4) activations (exp2 domain)
        const float uA = sigm2(gA);
        const float actA = uA * mA + bA;       // sigma(i) or tanh(g)
        const float actB = sigm2(gB);          // sigma(f) or sigma(o)
        // 5) cross-half exchange: all lanes get sI, tG, sF, sO for unit jj
        float sI, tG, sF, sO;
        half_bcast(actA, sI, tG);
        half_bcast(actB, sF, sO);
        // 6) state update (h_own valid in lanes 0..19, shadowed in 32..51)
        c_own = sF * c_own + sI * tG;
        h_own = sO * tanh_fast(c_own);
    };

    // 4-deep rotation; refills for the NEXT group issued at group top with
    // immediate offsets, consumed as register renames at group end.
    unsigned long long xq0 = xs[0], xq1 = xs[1], xq2 = xs[2], xq3 = xs[3];
    for (int tb = 0; tb < TT; tb += 4) {
        const unsigned long long xn0 = xs[tb + 4];
        const unsigned long long xn1 = xs[tb + 5];
        const unsigned long long xn2 = xs[tb + 6];
        const unsigned long long xn3 = xs[tb + 7];
        step(xq0);
        step(xq1);
        step(xq2);
        step(xq3);
        xq0 = xn0; xq1 = xn1; xq2 = xn2; xq3 = xn3;
    }

    // Epilogue: final h via readlane (f32), y = tanh(feat . conv_w + conv_b)
    float acc = conv_b[0];
    #pragma unroll
    for (int hh = 0; hh < HH; ++hh) acc += conv_w[hh] * bcast(h_own, hh);
    acc += conv_w[HH] * w[1 + cell];
    if (lane == 0) y_ws[cell] = tanh_fast(acc);
}

// Softmax over [1, y_0 .. y_1023] -> out[1025]
__global__ __launch_bounds__(256) void softmax_kernel(
    const float* __restrict__ y_ws, float* __restrict__ out)
{
    __shared__ float red[4];
    const int tid = threadIdx.x;
    float vals[5];
    float local = 0.0f;
    #pragma unroll
    for (int it = 0; it < 5; ++it) {
        const int idx = tid + it * 256;
        if (idx < NCELL + 1) {
            const float y = (idx == 0) ? 1.0f : y_ws[idx - 1];
            const float e = __expf(y);
            vals[it] = e;
            local += e;
        } else {
            vals[it] = 0.0f;
        }
    }
    #pragma unroll
    for (int off = 32; off > 0; off >>= 1) local += __shfl_down(local, off, 64);
    if ((tid & 63) == 0) red[tid >> 6] = local;
    __syncthreads();
    const float total = red[0] + red[1] + red[2] + red[3];
    const float inv = 1.0f / total;
    #pragma unroll
    for (int it = 0; it < 5; ++it) {
        const int idx = tid + it * 256;
        if (idx < NCELL + 1) out[idx] = vals[it] * inv;
    }
}

extern "C" void kernel_launch(void* const* d_in, const int* in_sizes, int n_in,
                              void* d_out, int out_size, void* d_ws, size_t ws_size,
                              hipStream_t stream) {
    const float* inp    = (const float*)d_in[0];
    const float* w      = (const float*)d_in[1];
    const float* W_ih   = (const float*)d_in[2];
    const float* W_hh   = (const float*)d_in[3];
    const float* b_ih   = (const float*)d_in[4];
    const float* b_hh   = (const float*)d_in[5];
    const float* conv_w = (const float*)d_in[6];
    const float* conv_b = (const float*)d_in[7];
    float* out  = (float*)d_out;
    float* y_ws = (float*)d_ws;

    lstm_kernel<<<NCELL, 64, 0, stream>>>(inp, W_ih, W_hh, b_ih, b_hh, w,
                                          conv_w, conv_b, y_ws);
    softmax_kernel<<<1, 256, 0, stream>>>(y_ws, out);
}